// Round 17
// baseline (169.369 us; speedup 1.0000x reference)
//
#include <hip/hip_runtime.h>

#define HW 4096      // 64*64 pixels per image
#define NC 256       // C_in
#define ND 256       // C_out
#define NB 16        // batch

typedef _Float16 half4_t __attribute__((ext_vector_type(4)));
typedef _Float16 half8_t __attribute__((ext_vector_type(8)));
typedef __fp16   fp16x2  __attribute__((ext_vector_type(2)));
typedef float floatx2 __attribute__((ext_vector_type(2)));
typedef float floatx4 __attribute__((ext_vector_type(4)));

#define MSCALE 64.0f                 // M scaled by 2^6 -> P,y scaled by 2^12
#define INV_MSCALE2 (1.0f / 4096.0f)
#define EPS_SCALED (1e-5f * 4096.0f * 4096.0f)   // eps for scaled-y stats

// ---------------------------------------------------------------------------
// prep: pack A-operand fragment streams, K-chunk-major:
//   addr = ((ks*16 + rt)*64 + l)*8 + j
// Also zeroes ssum/ssq (replaces a memset launch).
// ---------------------------------------------------------------------------
__global__ __launch_bounds__(256) void prep_weights(
        const float* __restrict__ w_core, const float* __restrict__ w_out,
        _Float16* __restrict__ W1p, _Float16* __restrict__ W2p,
        float* __restrict__ ssum) {
    int tid = blockIdx.x * 256 + threadIdx.x;   // 16384 threads
    if (tid < 8192) ssum[tid] = 0.f;            // ssum+ssq contiguous
    int l   = tid & 63;
    int rt  = (tid >> 6) & 15;
    int ks  = (tid >> 10) & 7;
    int sel = tid >> 13;
    int row = l & 15, kg = l >> 4;
    half8_t v;
    if (sel == 0) {
        int r = rt, k = row;
#pragma unroll
        for (int j = 0; j < 8; ++j) {
            int c = ks * 32 + kg * 8 + j;
            v[j] = (_Float16)(w_core[r * 4096 + c * 16 + k] * MSCALE);
        }
        *(half8_t*)&W1p[(size_t)((ks * 16 + rt) * 64 + l) * 8] = v;
    } else {
        int d = rt * 16 + row;
#pragma unroll
        for (int j = 0; j < 8; ++j) {
            int eg = ks * 32 + kg * 8 + j, e = eg >> 4, g = eg & 15;
            v[j] = (_Float16)w_out[g * 4096 + d * 16 + e];
        }
        *(half8_t*)&W2p[(size_t)((ks * 16 + rt) * 64 + l) * 8] = v;
    }
}

// ---------------------------------------------------------------------------
// 1-WAVE fused kernel: 64 threads = 1 wave per block, 16 pixels per block.
// ZERO __syncthreads: LDS (8 KB) is wave-private; compiler lgkmcnt ordering
// handles MT-write -> stage-B-read -> PL-write -> stage-C-read.
// Rationale (r9-r16): 4-wave blocks are phase-lockstepped by barriers and
// launch-bounds hints always spill; independent 1-wave blocks let 16
// waves/CU overlap freely. B-fragments (bx) load DIRECTLY global->reg
// (x[c][px] is exactly the MFMA B layout; 64B-coalesced per instruction).
// ---------------------------------------------------------------------------
template<bool F16Y>
__global__ __launch_bounds__(64) void compute_y(
        const float* __restrict__ x, const _Float16* __restrict__ W1p,
        const _Float16* __restrict__ W2p, float* __restrict__ y,
        _Float16* __restrict__ y16, float* __restrict__ ssum,
        float* __restrict__ ssq) {
    __shared__ __align__(16) _Float16 S[4096];   // 8 KB: MT -> PL overlay

    const int t = threadIdx.x;                   // lane 0..63
    const int a = blockIdx.x >> 8;               // 256 blocks per image
    const int pixbase = (blockIdx.x & 255) * 16;
    const int row16 = t & 15, kg = t >> 4;
    const float* xa = x + (size_t)a * NC * HW + pixbase + row16;

    // ---- bx: B-fragments direct from global; lane l covers
    //      (c = ks*32 + kg*8 + j, px = row16). 64 loads, 64B segments. ----
    half8_t bx[8];
#pragma unroll
    for (int ks = 0; ks < 8; ++ks) {
        float xr[8];
#pragma unroll
        for (int j = 0; j < 8; ++j)
            xr[j] = xa[(size_t)(ks * 32 + kg * 8 + j) * HW];
#pragma unroll
        for (int j = 0; j < 8; ++j) bx[ks][j] = (_Float16)xr[j];
    }

    // ---- stage A: MT = W1T.x, rt-group blocked (acc = 16 VGPR/group) ----
    const half8_t* W1v = (const half8_t*)W1p;
    {
        half8_t af[4], afn[4];
#pragma unroll
        for (int rq = 0; rq < 4; ++rq) af[rq] = W1v[rq * 64 + t];  // rtg0,ks0
#pragma unroll
        for (int rtg = 0; rtg < 4; ++rtg) {
            floatx4 acc[4];
#pragma unroll
            for (int rq = 0; rq < 4; ++rq) acc[rq] = (floatx4){0.f,0.f,0.f,0.f};
#pragma unroll
            for (int ks = 0; ks < 8; ++ks) {
                const bool last = (rtg == 3) && (ks == 7);
                const int nrtg = (ks == 7) ? rtg + 1 : rtg;
                const int nks  = (ks == 7) ? 0 : ks + 1;
                if (!last) {
#pragma unroll
                    for (int rq = 0; rq < 4; ++rq)
                        afn[rq] = W1v[(nks * 16 + nrtg * 4 + rq) * 64 + t];
                }
#pragma unroll
                for (int rq = 0; rq < 4; ++rq)
                    acc[rq] = __builtin_amdgcn_mfma_f32_16x16x32_f16(
                                  af[rq], bx[ks], acc[rq], 0, 0, 0);
#pragma unroll
                for (int rq = 0; rq < 4; ++rq) af[rq] = afn[rq];
            }
            // MT write: col = px = l&15, rows rk = rt*16 + kg*4 + r2
#pragma unroll
            for (int rq = 0; rq < 4; ++rq) {
                const int u = (rtg * 4 + rq) * 4 + kg;    // half4 unit
                half4_t hv;
#pragma unroll
                for (int r2 = 0; r2 < 4; ++r2) hv[r2] = (_Float16)acc[rq][r2];
                *(half4_t*)&S[row16 * 256 + ((u ^ row16) << 2)] = hv;
            }
        }
    }

    // ---- stage B: per-pixel P = M*M (4 threads/pixel), f4-blocked ----
    {
        const int p = t >> 2, qe = t & 3, ps = p;
        const _Float16* Mp = &S[p * 256];
        floatx2 Pacc[4][8];
#pragma unroll
        for (int i = 0; i < 4; ++i)
#pragma unroll
            for (int g2 = 0; g2 < 8; ++g2) Pacc[i][g2] = (floatx2){0.f, 0.f};
#pragma unroll
        for (int f4 = 0; f4 < 4; ++f4) {
            float Afb[4][4];
#pragma unroll
            for (int i = 0; i < 4; ++i) {
                const int e = i * 4 + qe;
                half4_t v = *(const half4_t*)&Mp[(((e * 4 + f4) ^ ps) << 2)];
#pragma unroll
                for (int j = 0; j < 4; ++j) Afb[i][j] = (float)v[j];
            }
#pragma unroll
            for (int fl = 0; fl < 4; ++fl) {
                const int f = f4 * 4 + fl;
                floatx2 Bg[8];
#pragma unroll
                for (int g4 = 0; g4 < 4; ++g4) {
                    half4_t v = *(const half4_t*)
                        &Mp[(((f * 4 + g4) ^ ps) << 2)];   // broadcast across qe
                    Bg[g4 * 2]     = (floatx2){(float)v[0], (float)v[1]};
                    Bg[g4 * 2 + 1] = (floatx2){(float)v[2], (float)v[3]};
                }
#pragma unroll
                for (int i = 0; i < 4; ++i) {
                    floatx2 a2 = {Afb[i][fl], Afb[i][fl]};
#pragma unroll
                    for (int g2 = 0; g2 < 8; ++g2)
                        Pacc[i][g2] = __builtin_elementwise_fma(a2, Bg[g2],
                                                                Pacc[i][g2]);
                }
            }
        }
        // PL write (overlays MT row p; single wave -> ds ordering is enough)
#pragma unroll
        for (int i = 0; i < 4; ++i) {
            const int e = i * 4 + qe;
#pragma unroll
            for (int h2 = 0; h2 < 2; ++h2) {
                half8_t hv;
#pragma unroll
                for (int g2 = 0; g2 < 4; ++g2) {
                    fp16x2 pk = __builtin_amdgcn_cvt_pkrtz(
                        Pacc[i][h2 * 4 + g2][0], Pacc[i][h2 * 4 + g2][1]);
                    hv[g2 * 2]     = (_Float16)pk[0];
                    hv[g2 * 2 + 1] = (_Float16)pk[1];
                }
                *(half8_t*)&S[p * 256 + (((e * 2 + h2) ^ ps) << 3)] = hv;
            }
        }
    }

    // ---- stage C: yT = W2T.P, dt-group blocked, fused epilogue ----
    const half8_t* W2v = (const half8_t*)W2p;
    float*    ya   = y   + (size_t)a * ND * HW + pixbase;
    _Float16* ya16 = F16Y ? (y16 + (size_t)a * ND * HW + pixbase) : nullptr;
    {
        half8_t caf[4], cafn[4];
#pragma unroll
        for (int dq = 0; dq < 4; ++dq) caf[dq] = W2v[dq * 64 + t];
#pragma unroll
        for (int dtg = 0; dtg < 4; ++dtg) {
            floatx4 cacc[4];
#pragma unroll
            for (int dq = 0; dq < 4; ++dq) cacc[dq] = (floatx4){0.f,0.f,0.f,0.f};
#pragma unroll
            for (int ks = 0; ks < 8; ++ks) {
                const bool last = (dtg == 3) && (ks == 7);
                const int ndtg = (ks == 7) ? dtg + 1 : dtg;
                const int nks  = (ks == 7) ? 0 : ks + 1;
                if (!last) {
#pragma unroll
                    for (int dq = 0; dq < 4; ++dq)
                        cafn[dq] = W2v[(nks * 16 + ndtg * 4 + dq) * 64 + t];
                }
                half8_t bf = *(const half8_t*)
                    &S[row16 * 256 + (((ks * 4 + kg) ^ row16) << 3)];
#pragma unroll
                for (int dq = 0; dq < 4; ++dq)
                    cacc[dq] = __builtin_amdgcn_mfma_f32_16x16x32_f16(
                                   caf[dq], bf, cacc[dq], 0, 0, 0);
#pragma unroll
                for (int dq = 0; dq < 4; ++dq) caf[dq] = cafn[dq];
            }
            // fused epilogue for these 16 d rows
#pragma unroll
            for (int dq = 0; dq < 4; ++dq) {
                const int dbase = (dtg * 4 + dq) * 16 + kg * 4;
#pragma unroll
                for (int r2 = 0; r2 < 4; ++r2) {
                    const int d = dbase + r2;
                    float v;
                    if (F16Y) {
                        _Float16 hv = (_Float16)cacc[dq][r2];   // ys = 4096*y
                        ya16[(size_t)d * HW + row16] = hv;
                        v = (float)hv;
                    } else {
                        v = cacc[dq][r2] * INV_MSCALE2;
                        ya[(size_t)d * HW + row16] = v;
                    }
                    float s = v, q2 = v * v;
#pragma unroll
                    for (int off = 1; off < 16; off <<= 1) {
                        s  += __shfl_xor(s, off);
                        q2 += __shfl_xor(q2, off);
                    }
                    if (row16 == 0) {
                        atomicAdd(&ssum[a * 256 + d], s);
                        atomicAdd(&ssq [a * 256 + d], q2);
                    }
                }
            }
        }
    }
}

// ---------------------------------------------------------------------------
// finalize (f16 path): one block per (a,d); stats computed inline
// ---------------------------------------------------------------------------
__global__ __launch_bounds__(256) void finalize_f16(
        const _Float16* __restrict__ y16, const float* __restrict__ ssum,
        const float* __restrict__ ssq, float* __restrict__ out) {
    const int ad = blockIdx.x;
    const float m  = ssum[ad] * (1.f / HW);
    const float sv = ssq[ad] * (1.f / HW) - m * m;
    const float s  = rsqrtf(sv + EPS_SCALED);
    const size_t base = (size_t)ad * HW + threadIdx.x * 16;
    half8_t h0 = *(const half8_t*)&y16[base];
    half8_t h1 = *(const half8_t*)&y16[base + 8];
    float o[16];
#pragma unroll
    for (int j = 0; j < 8; ++j) {
        float z0 = ((float)h0[j] - m) * s;
        float z1 = ((float)h1[j] - m) * s;
        o[j]     = z0 / (1.f + fabsf(z0));
        o[8 + j] = z1 / (1.f + fabsf(z1));
    }
#pragma unroll
    for (int q = 0; q < 4; ++q)
        *(float4*)&out[base + q * 4] =
            make_float4(o[q * 4], o[q * 4 + 1], o[q * 4 + 2], o[q * 4 + 3]);
}

// ---------------------------------------------------------------------------
// finalize (f32 fallback): in-place on d_out, inline stats
// ---------------------------------------------------------------------------
__global__ __launch_bounds__(256) void finalize_f32(
        float* __restrict__ y, const float* __restrict__ ssum,
        const float* __restrict__ ssq) {
    const int i4 = blockIdx.x * 256 + threadIdx.x;
    const int ad = i4 >> 10;
    const float m  = ssum[ad] * (1.f / HW);
    const float sv = ssq[ad] * (1.f / HW) - m * m;
    const float s  = rsqrtf(sv + 1e-5f);
    float4 v = ((const float4*)y)[i4];
    float vv[4] = {v.x, v.y, v.z, v.w};
#pragma unroll
    for (int lq = 0; lq < 4; ++lq) {
        float z = (vv[lq] - m) * s;
        vv[lq] = z / (1.f + fabsf(z));
    }
    ((float4*)y)[i4] = make_float4(vv[0], vv[1], vv[2], vv[3]);
}

// ---------------------------------------------------------------------------
extern "C" void kernel_launch(void* const* d_in, const int* in_sizes, int n_in,
                              void* d_out, int out_size, void* d_ws, size_t ws_size,
                              hipStream_t stream) {
    const float* x      = (const float*)d_in[0];
    const float* w_core = (const float*)d_in[1];
    const float* w_out  = (const float*)d_in[2];
    float* y = (float*)d_out;

    char* wsb = (char*)d_ws;
    _Float16* W1p = (_Float16*)wsb;                       // 128KB
    _Float16* W2p = (_Float16*)(wsb + 131072);            // 128KB
    float* ssum   = (float*)(wsb + 262144);               // 16KB
    float* ssq    = (float*)(wsb + 278528);               // 16KB
    _Float16* y16 = (_Float16*)(wsb + 294912);            // 32MB (f16 path)

    const size_t need_f16 = 294912 + (size_t)NB * ND * HW * sizeof(_Float16);
    const bool use_f16 = ws_size >= need_f16;

    prep_weights<<<64, 256, 0, stream>>>(w_core, w_out, W1p, W2p, ssum);
    if (use_f16) {
        compute_y<true><<<4096, 64, 0, stream>>>(x, W1p, W2p, y, y16, ssum, ssq);
        finalize_f16<<<4096, 256, 0, stream>>>(y16, ssum, ssq, y);
    } else {
        compute_y<false><<<4096, 64, 0, stream>>>(x, W1p, W2p, y, nullptr, ssum, ssq);
        finalize_f32<<<16384, 256, 0, stream>>>(y, ssum, ssq);
    }
}